// Round 9
// baseline (964.732 us; speedup 1.0000x reference)
//
#include <hip/hip_runtime.h>
#include <hip/hip_bf16.h>

#define BSZ 8
#define PAIRS 5
#define NCH 2
#define HWP 128
#define PP 64
#define DIM 512
#define NHEAD 8
#define DHEAD 64
#define DFF 2048
#define NLAYER 6
#define SEQ 640
#define NTOK (BSZ * SEQ)   // 5120
#define FIN 10
#define MPOST (BSZ * PAIRS * PP)   // 2560

typedef unsigned short u16;
typedef __bf16 bf16_t;
typedef __attribute__((ext_vector_type(8))) __bf16 bf16x8;
typedef __attribute__((ext_vector_type(8))) unsigned short u16x8;
typedef __attribute__((ext_vector_type(4))) float f32x4;
#define MFMA16(a, b, c) __builtin_amdgcn_mfma_f32_16x16x32_bf16(a, b, c, 0, 0, 0)

__device__ __forceinline__ u16 f2b(float x) {   // RNE f32->bf16
  unsigned u = __float_as_uint(x);
  return (u16)((u + 0x7fffu + ((u >> 16) & 1u)) >> 16);
}

// tanh-form GELU (error vs exact erf-GELU <~1e-3; margin is 0.032)
__device__ __forceinline__ float gelu_t(float x) {
  float y = 0.7978845608f * (x + 0.044715f * x * x * x);
  y = fminf(fmaxf(y, -10.f), 10.f);
  float e = __expf(2.f * y);
  return 0.5f * x * (1.f + (e - 1.f) / (e + 1.f));
}

// async global->LDS DMA, 16B/lane; LDS dest = wave-uniform base + lane*16
__device__ __forceinline__ void dma16(const u16* g, void* l) {
  __builtin_amdgcn_global_load_lds(
      (const __attribute__((address_space(1))) void*)g,
      (__attribute__((address_space(3))) void*)l, 16, 0, 0);
}

#define W_QKV (3 * DIM * DIM)   // 786432
#define W_O (DIM * DIM)         // 262144
#define W_1 (DFF * DIM)         // 1048576
#define OFF_O W_QKV
#define OFF_1 (W_QKV + W_O)
#define OFF_2 (W_QKV + W_O + W_1)
#define W_ALL (W_QKV + W_O + 2 * W_1)   // 3145728
#define PREPOST (2 * DIM * DIM)         // 524288
#define N_CVT (PREPOST + NLAYER * W_ALL)   // 19398656

// ---------------- ALL weights f32->bf16, 8 elems/thread, 16B stores
__global__ __launch_bounds__(256) void k_cvt_all(const float* __restrict__ preW,
                                                 const float* __restrict__ postW,
                                                 const float* __restrict__ wq,
                                                 const float* __restrict__ wo,
                                                 const float* __restrict__ w1,
                                                 const float* __restrict__ w2,
                                                 u16* __restrict__ dst) {
  size_t i = ((size_t)blockIdx.x * 256 + threadIdx.x) * 8;   // < N_CVT
  const float* src;
  size_t off;
  if (i < DIM * DIM) { src = preW; off = i; }
  else if (i < PREPOST) { src = postW; off = i - DIM * DIM; }
  else {
    size_t j = i - PREPOST;
    int l = (int)(j / W_ALL);
    size_t r = j - (size_t)l * W_ALL;
    if (r < OFF_O) { src = wq + (size_t)l * W_QKV; off = r; }
    else if (r < OFF_1) { src = wo + (size_t)l * W_O; off = r - OFF_O; }
    else if (r < OFF_2) { src = w1 + (size_t)l * W_1; off = r - OFF_1; }
    else { src = w2 + (size_t)l * W_1; off = r - OFF_2; }
  }
  float4 v0 = *(const float4*)(src + off);
  float4 v1 = *(const float4*)(src + off + 4);
  u16x8 o;
  o[0] = f2b(v0.x); o[1] = f2b(v0.y); o[2] = f2b(v0.z); o[3] = f2b(v0.w);
  o[4] = f2b(v1.x); o[5] = f2b(v1.y); o[6] = f2b(v1.z); o[7] = f2b(v1.w);
  *(u16x8*)(dst + i) = o;
}

// ---------------- patchify -> bf16 A[NTOK][512]
__global__ __launch_bounds__(256) void k_patchify(const float* __restrict__ init,
                                                  const float* __restrict__ endp,
                                                  u16* __restrict__ A) {
  int i = blockIdx.x * 256 + threadIdx.x;
  int d = i & 511;
  int g = i >> 9;
  int p = g & 63;
  int fi = (g >> 6) % FIN;
  int b = g / SEQ;
  int e = fi & 1;
  int pr = fi >> 1;
  int c = d >> 8;
  int r1 = (d >> 4) & 15;
  int r2 = d & 15;
  int row = ((p >> 3) << 4) + r1;
  int col = ((p & 7) << 4) + r2;
  const float* src = e ? endp : init;
  size_t off = ((size_t)((b * PAIRS + pr) * NCH + c) << 14) + (size_t)row * HWP + col;
  A[i] = f2b(src[off]);
}

// ---------------- bf16 MFMA GEMM, 4-stage DMA pipeline (3 tiles in flight;
// wait vmcnt(3*NC): consumed tile's DMA was issued 3 compute periods ago).
// Tile 64(M) x NT(N), BK=32, 4 waves 2x2.
// MODE 0: outB = act(A·B^T + bias) bf16
// MODE 1: outP slice z = raw f32 partial
// MODE 2: pre epilogue: +bias+patch_pos+func_pos -> outF f32 + outB bf16
// MODE 3: post epilogue: +bias, depatchify scatter -> outF; A rows gathered
template <int NT, int MODE>
__global__ __launch_bounds__(256) void k_mma(const u16* __restrict__ A,
                                             const u16* __restrict__ B,
                                             const float* __restrict__ bias,
                                             u16* __restrict__ outB,
                                             float* __restrict__ outP,
                                             float* __restrict__ outF,
                                             const float* __restrict__ pp,
                                             const float* __restrict__ fp,
                                             int M, int N, int K, int Kblk, int act) {
  constexpr int FJ = NT / 32;             // N-frags per wave
  constexpr int NC = (4 + NT / 16) / 4;   // DMA instrs per wave per stage
  __shared__ __align__(16) bf16_t As[4][64][32];
  __shared__ __align__(16) bf16_t Bs[4][NT][32];
  const int t = threadIdx.x;
  const int w = t >> 6, lane = t & 63, quad = lane >> 4, l16 = lane & 15;
  int bx = blockIdx.x, by = blockIdx.y;
  if ((gridDim.y & 7) == 0) {       // XCD swizzle
    int lin = bx + gridDim.x * by;
    int YT = gridDim.y >> 3;
    int xcd = lin & 7, slot = lin >> 3;
    by = xcd * YT + slot % YT;
    bx = slot / YT;
  }
  const int row0 = by << 6, col0 = bx * NT;
  const size_t kOff = (size_t)blockIdx.z * Kblk;
  const int mB = (w & 1) << 5;          // 0 or 32
  const int nB = (w >> 1) * (NT / 2);

  // per-lane A-chunk source pointers (MODE 3 gathers init-slot token rows)
  const u16* aP[4];
#pragma unroll
  for (int c = 0; c < 4; ++c) {
    int r = row0 + c * 16 + (lane >> 2);
    int g = r;
    if (MODE == 3) {
      int p = r & 63, pr = (r >> 6) % PAIRS, b = r / (PAIRS * PP);
      g = b * SEQ + pr * 128 + p;
    }
    aP[c] = A + (size_t)g * K + kOff + ((lane & 3) << 3);
  }
  const u16* bP = B + (size_t)(col0 + (lane >> 2)) * K + kOff + ((lane & 3) << 3);

  f32x4 acc[2][FJ];
#pragma unroll
  for (int i = 0; i < 2; ++i)
#pragma unroll
    for (int j = 0; j < FJ; ++j) acc[i][j] = (f32x4){0.f, 0.f, 0.f, 0.f};

  auto stage = [&](int bu, int kk) {
#pragma unroll
    for (int s = 0; s < NC; ++s) {
      int c = NC * w + s;
      if (c < 4) dma16(aP[c] + kk, &As[bu][c * 16][0]);
      else dma16(bP + (size_t)((c - 4) * 16) * K + kk, &Bs[bu][(c - 4) * 16][0]);
    }
  };

  const int iters = Kblk >> 5;   // >= 16 always
  stage(0, 0);
  stage(1, 32);
  stage(2, 64);
  for (int it = 0; it < iters; ++it) {
    const int cur = it & 3;
    if (it > 0) asm volatile("s_barrier" ::: "memory");  // readers of reused buf done
    if (it + 3 < iters) stage((it + 3) & 3, (it + 3) << 5);  // stays in flight
    const int ahead = (iters - 1 - it) < 3 ? (iters - 1 - it) : 3;
    if (NC == 2) {
      if (ahead == 3) asm volatile("s_waitcnt vmcnt(6)" ::: "memory");
      else if (ahead == 2) asm volatile("s_waitcnt vmcnt(4)" ::: "memory");
      else if (ahead == 1) asm volatile("s_waitcnt vmcnt(2)" ::: "memory");
      else asm volatile("s_waitcnt vmcnt(0)" ::: "memory");
    } else {
      if (ahead == 3) asm volatile("s_waitcnt vmcnt(9)" ::: "memory");
      else if (ahead == 2) asm volatile("s_waitcnt vmcnt(6)" ::: "memory");
      else if (ahead == 1) asm volatile("s_waitcnt vmcnt(3)" ::: "memory");
      else asm volatile("s_waitcnt vmcnt(0)" ::: "memory");
    }
    asm volatile("s_barrier" ::: "memory");              // all waves' cur DMAs landed
    bf16x8 af[2], bfr[FJ];
#pragma unroll
    for (int i = 0; i < 2; ++i)
      af[i] = *(const bf16x8*)&As[cur][mB + i * 16 + l16][quad * 8];
#pragma unroll
    for (int j = 0; j < FJ; ++j)
      bfr[j] = *(const bf16x8*)&Bs[cur][nB + j * 16 + l16][quad * 8];
#pragma unroll
    for (int i = 0; i < 2; ++i)
#pragma unroll
      for (int j = 0; j < FJ; ++j) acc[i][j] = MFMA16(af[i], bfr[j], acc[i][j]);
  }

#pragma unroll
  for (int i = 0; i < 2; ++i)
#pragma unroll
    for (int reg = 0; reg < 4; ++reg) {
      int m = row0 + mB + i * 16 + quad * 4 + reg;
#pragma unroll
      for (int j = 0; j < FJ; ++j) {
        int n = col0 + nB + j * 16 + l16;
        float v = acc[i][j][reg];
        if (MODE == 0) {
          v += bias[n];
          if (act) v = gelu_t(v);
          outB[(size_t)m * N + n] = f2b(v);
        } else if (MODE == 1) {
          outP[(size_t)blockIdx.z * M * N + (size_t)m * N + n] = v;
        } else if (MODE == 2) {
          int p = m & 63, fi = (m >> 6) % FIN;
          v += bias[n] + pp[p * DIM + n] + fp[fi * DIM + n];
          outF[(size_t)m * N + n] = v;
          outB[(size_t)m * N + n] = f2b(v);
        } else {   // MODE 3: depatchify scatter
          v += bias[n];
          int p = m & 63, pr = (m >> 6) % PAIRS, b = m / (PAIRS * PP);
          int c = n >> 8, r1 = (n >> 4) & 15, r2 = n & 15;
          int row = ((p >> 3) << 4) + r1, col = ((p & 7) << 4) + r2;
          size_t off = ((size_t)((b * PAIRS + pr) * NCH + c) << 14) +
                       (size_t)row * HWP + col;
          outF[off] = v;
        }
      }
    }
}

// ---------------- fused flash attention (bf16 MFMA) with next-tile reg prefetch.
__global__ __launch_bounds__(256) void k_attn(const u16* __restrict__ qkv,
                                              u16* __restrict__ o) {
  __shared__ bf16_t Qs[64][72];
  __shared__ bf16_t Ks[64][72];
  __shared__ bf16_t Vs[64][72];   // transposed: Vs[d][tok]
  __shared__ bf16_t Ps[64][72];
  const int t = threadIdx.x;
  const int w = t >> 6, lane = t & 63, quad = lane >> 4, l16 = lane & 15;
  const int qblk = blockIdx.x, h = blockIdx.y, b = blockIdx.z;
  const int q0 = qblk << 6;
  const u16* base = qkv + (size_t)b * SEQ * (3 * DIM);
  const int sr = t >> 2;
  const int sd = (t & 3) << 4;
  const int rowB = 3 * DIM;
  {
    const u16* qp = base + (size_t)(q0 + sr) * rowB + h * DHEAD + sd;
    *(bf16x8*)&Qs[sr][sd] = *(const bf16x8*)(const void*)qp;
    *(bf16x8*)&Qs[sr][sd + 8] = *(const bf16x8*)(const void*)(qp + 8);
  }
  __syncthreads();
  bf16x8 aQ0 = *(const bf16x8*)&Qs[w * 16 + l16][quad * 8];
  bf16x8 aQ1 = *(const bf16x8*)&Qs[w * 16 + l16][32 + quad * 8];
  f32x4 accO[4];
#pragma unroll
  for (int j = 0; j < 4; ++j) accO[j] = (f32x4){0.f, 0.f, 0.f, 0.f};
  float mSt[4] = {-1e30f, -1e30f, -1e30f, -1e30f};
  float lSt[4] = {0.f, 0.f, 0.f, 0.f};
  const int ntile = qblk + 1;
  const u16* kp0 = base + (size_t)sr * rowB + DIM + h * DHEAD + sd;
  const u16* vp0 = base + (size_t)sr * rowB + 2 * DIM + h * DHEAD + sd;
  bf16x8 kR0 = *(const bf16x8*)(const void*)kp0;
  bf16x8 kR1 = *(const bf16x8*)(const void*)(kp0 + 8);
  bf16x8 vR0 = *(const bf16x8*)(const void*)vp0;
  bf16x8 vR1 = *(const bf16x8*)(const void*)(vp0 + 8);
  for (int kt = 0; kt < ntile; ++kt) {
    *(bf16x8*)&Ks[sr][sd] = kR0;
    *(bf16x8*)&Ks[sr][sd + 8] = kR1;
#pragma unroll
    for (int e = 0; e < 8; ++e) Vs[sd + e][sr] = vR0[e];
#pragma unroll
    for (int e = 0; e < 8; ++e) Vs[sd + 8 + e][sr] = vR1[e];
    if (kt + 1 < ntile) {   // prefetch tile kt+1
      const u16* kp = kp0 + (size_t)(kt + 1) * 64 * rowB;
      const u16* vp = vp0 + (size_t)(kt + 1) * 64 * rowB;
      kR0 = *(const bf16x8*)(const void*)kp;
      kR1 = *(const bf16x8*)(const void*)(kp + 8);
      vR0 = *(const bf16x8*)(const void*)vp;
      vR1 = *(const bf16x8*)(const void*)(vp + 8);
    }
    __syncthreads();
    f32x4 s[4];
#pragma unroll
    for (int j = 0; j < 4; ++j) {
      bf16x8 b0 = *(const bf16x8*)&Ks[j * 16 + l16][quad * 8];
      bf16x8 b1 = *(const bf16x8*)&Ks[j * 16 + l16][32 + quad * 8];
      s[j] = (f32x4){0.f, 0.f, 0.f, 0.f};
      s[j] = MFMA16(aQ0, b0, s[j]);
      s[j] = MFMA16(aQ1, b1, s[j]);
      s[j] *= 0.125f;
    }
#pragma unroll
    for (int reg = 0; reg < 4; ++reg) {
      float mx = fmaxf(fmaxf(s[0][reg], s[1][reg]), fmaxf(s[2][reg], s[3][reg]));
      mx = fmaxf(mx, __shfl_xor(mx, 1));
      mx = fmaxf(mx, __shfl_xor(mx, 2));
      mx = fmaxf(mx, __shfl_xor(mx, 4));
      mx = fmaxf(mx, __shfl_xor(mx, 8));
      float mNew = fmaxf(mSt[reg], mx);
      float alpha = __expf(mSt[reg] - mNew);
      mSt[reg] = mNew;
      float rs = 0.f;
#pragma unroll
      for (int j = 0; j < 4; ++j) {
        float p = __expf(s[j][reg] - mNew);
        s[j][reg] = p;
        rs += p;
      }
      rs += __shfl_xor(rs, 1);
      rs += __shfl_xor(rs, 2);
      rs += __shfl_xor(rs, 4);
      rs += __shfl_xor(rs, 8);
      lSt[reg] = lSt[reg] * alpha + rs;
#pragma unroll
      for (int j = 0; j < 4; ++j) accO[j][reg] *= alpha;
    }
#pragma unroll
    for (int j = 0; j < 4; ++j)
#pragma unroll
      for (int reg = 0; reg < 4; ++reg)
        *(u16*)&Ps[w * 16 + quad * 4 + reg][j * 16 + l16] = f2b(s[j][reg]);
    __syncthreads();
    bf16x8 aP0 = *(const bf16x8*)&Ps[w * 16 + l16][quad * 8];
    bf16x8 aP1 = *(const bf16x8*)&Ps[w * 16 + l16][32 + quad * 8];
#pragma unroll
    for (int jd = 0; jd < 4; ++jd) {
      bf16x8 b0 = *(const bf16x8*)&Vs[jd * 16 + l16][quad * 8];
      bf16x8 b1 = *(const bf16x8*)&Vs[jd * 16 + l16][32 + quad * 8];
      accO[jd] = MFMA16(aP0, b0, accO[jd]);
      accO[jd] = MFMA16(aP1, b1, accO[jd]);
    }
    __syncthreads();
  }
#pragma unroll
  for (int reg = 0; reg < 4; ++reg) {
    float inv = 1.0f / lSt[reg];
    int row = q0 + w * 16 + quad * 4 + reg;
#pragma unroll
    for (int jd = 0; jd < 4; ++jd)
      o[((size_t)(b * SEQ + row)) * DIM + h * DHEAD + jd * 16 + l16] =
          f2b(accO[jd][reg] * inv);
  }
}

// ---------------- split-K reduce + bias + residual + LayerNorm (one row/block)
__global__ __launch_bounds__(256) void k_red_ln(const float* __restrict__ part, int KS,
                                                const float* __restrict__ bias,
                                                float* __restrict__ f,
                                                u16* __restrict__ fb,
                                                const float* __restrict__ s,
                                                const float* __restrict__ bvec) {
  const int row = blockIdx.x;
  const int t = threadIdx.x;
  const size_t base = (size_t)row * DIM;
  float x0 = f[base + t] + bias[t];
  float x1 = f[base + t + 256] + bias[t + 256];
  for (int z = 0; z < KS; ++z) {
    x0 += part[(size_t)z * NTOK * DIM + base + t];
    x1 += part[(size_t)z * NTOK * DIM + base + t + 256];
  }
  float sum = x0 + x1;
  float sq = x0 * x0 + x1 * x1;
#pragma unroll
  for (int off = 32; off; off >>= 1) {
    sum += __shfl_xor(sum, off);
    sq += __shfl_xor(sq, off);
  }
  __shared__ float rs[4], rq[4];
  const int w = t >> 6, lane = t & 63;
  if (lane == 0) { rs[w] = sum; rq[w] = sq; }
  __syncthreads();
  float tot = rs[0] + rs[1] + rs[2] + rs[3];
  float tq2 = rq[0] + rq[1] + rq[2] + rq[3];
  float mu = tot * (1.0f / 512.0f);
  float var = tq2 * (1.0f / 512.0f) - mu * mu;
  float rstd = rsqrtf(var + 1e-5f);
  float v0 = (x0 - mu) * rstd * s[t] + bvec[t];
  float v1 = (x1 - mu) * rstd * s[t + 256] + bvec[t + 256];
  f[base + t] = v0;
  f[base + t + 256] = v1;
  fb[base + t] = f2b(v0);
  fb[base + t + 256] = f2b(v1);
}

extern "C" void kernel_launch(void* const* d_in, const int* in_sizes, int n_in,
                              void* d_out, int out_size, void* d_ws, size_t ws_size,
                              hipStream_t stream) {
  const float* init = (const float*)d_in[0];
  const float* endp = (const float*)d_in[1];
  const float* pre_W = (const float*)d_in[3];
  const float* pre_b = (const float*)d_in[4];
  const float* post_W = (const float*)d_in[5];
  const float* post_b = (const float*)d_in[6];
  const float* patch_pos = (const float*)d_in[7];
  const float* func_pos = (const float*)d_in[8];
  const float* Wqkv = (const float*)d_in[9];
  const float* bqkv = (const float*)d_in[10];
  const float* Wo = (const float*)d_in[11];
  const float* bo = (const float*)d_in[12];
  const float* ln1_s = (const float*)d_in[13];
  const float* ln1_b = (const float*)d_in[14];
  const float* ln2_s = (const float*)d_in[15];
  const float* ln2_b = (const float*)d_in[16];
  const float* W1 = (const float*)d_in[17];
  const float* b1 = (const float*)d_in[18];
  const float* W2 = (const float*)d_in[19];
  const float* b2 = (const float*)d_in[20];
  float* out = (float*)d_out;

  // ws layout (~102 MB; ws is 256 MB)
  char* p = (char*)d_ws;
  float* buf_f = (float*)p;    p += (size_t)NTOK * DIM * 4;    // f32 residual master
  u16* buf_fb = (u16*)p;       p += (size_t)NTOK * DIM * 2;    // bf16 stream
  u16* buf_attn = (u16*)p;     p += (size_t)NTOK * DIM * 2;
  u16* shared_b = (u16*)p;     p += (size_t)NTOK * DFF * 2;    // patch/qkv/hid alias
  u16* wAll = (u16*)p;         p += (size_t)N_CVT * 2;         // ALL weights bf16
  float* partial = (float*)p;  // 2 * NTOK * DIM * 4
  u16* buf_patch = shared_b;
  u16* buf_qkv = shared_b;
  u16* buf_hid = shared_b;
  u16* wPre = wAll;
  u16* wPost = wAll + DIM * DIM;
  u16* wL = wAll + PREPOST;

  dim3 blk(256);
  const int elems = NTOK * DIM;

  k_cvt_all<<<N_CVT / (256 * 8), blk, 0, stream>>>(pre_W, post_W, Wqkv, Wo, W1, W2,
                                                   wAll);
  k_patchify<<<elems / 256, blk, 0, stream>>>(init, endp, buf_patch);
  // pre GEMM fused with bias+pos epilogue -> buf_f (f32) + buf_fb (bf16)
  k_mma<64, 2><<<dim3(8, 80, 1), blk, 0, stream>>>(
      buf_patch, wPre, pre_b, buf_fb, nullptr, buf_f, patch_pos, func_pos,
      NTOK, DIM, DIM, DIM, 0);

  for (int l = 0; l < NLAYER; ++l) {
    u16* wB = wL + (size_t)l * W_ALL;
    k_mma<128, 0><<<dim3(12, 80, 1), blk, 0, stream>>>(
        buf_fb, wB, bqkv + (size_t)l * 3 * DIM, buf_qkv, nullptr, nullptr, nullptr,
        nullptr, NTOK, 3 * DIM, DIM, DIM, 0);
    k_attn<<<dim3(SEQ / 64, NHEAD, BSZ), blk, 0, stream>>>(buf_qkv, buf_attn);
    k_mma<64, 1><<<dim3(8, 80, 1), blk, 0, stream>>>(
        buf_attn, wB + OFF_O, nullptr, nullptr, partial, nullptr, nullptr, nullptr,
        NTOK, DIM, DIM, DIM, 0);
    k_red_ln<<<NTOK, blk, 0, stream>>>(partial, 1, bo + (size_t)l * DIM, buf_f,
                                       buf_fb, ln1_s + (size_t)l * DIM,
                                       ln1_b + (size_t)l * DIM);
    k_mma<128, 0><<<dim3(16, 80, 1), blk, 0, stream>>>(
        buf_fb, wB + OFF_1, b1 + (size_t)l * DFF, buf_hid, nullptr, nullptr, nullptr,
        nullptr, NTOK, DFF, DIM, DIM, 1);
    k_mma<64, 1><<<dim3(8, 80, 2), blk, 0, stream>>>(
        buf_hid, wB + OFF_2, nullptr, nullptr, partial, nullptr, nullptr, nullptr,
        NTOK, DIM, DFF, DFF / 2, 0);
    k_red_ln<<<NTOK, blk, 0, stream>>>(partial, 2, b2 + (size_t)l * DIM, buf_f,
                                       buf_fb, ln2_s + (size_t)l * DIM,
                                       ln2_b + (size_t)l * DIM);
  }

  // post GEMM: gathered A rows (prologue) + bias + depatchify scatter (epilogue)
  k_mma<64, 3><<<dim3(8, 40, 1), blk, 0, stream>>>(
      buf_fb, wPost, post_b, nullptr, nullptr, out, nullptr, nullptr,
      MPOST, DIM, DIM, DIM, 0);
}

// Round 10
// 904.164 us; speedup vs baseline: 1.0670x; 1.0670x over previous
//
#include <hip/hip_runtime.h>
#include <hip/hip_bf16.h>

#define BSZ 8
#define PAIRS 5
#define NCH 2
#define HWP 128
#define PP 64
#define DIM 512
#define NHEAD 8
#define DHEAD 64
#define DFF 2048
#define NLAYER 6
#define SEQ 640
#define NTOK (BSZ * SEQ)   // 5120
#define FIN 10
#define MPOST (BSZ * PAIRS * PP)   // 2560

typedef unsigned short u16;
typedef __bf16 bf16_t;
typedef __attribute__((ext_vector_type(8))) __bf16 bf16x8;
typedef __attribute__((ext_vector_type(8))) unsigned short u16x8;
typedef __attribute__((ext_vector_type(4))) unsigned short u16x4;
typedef __attribute__((ext_vector_type(4))) float f32x4;
#define MFMA16(a, b, c) __builtin_amdgcn_mfma_f32_16x16x32_bf16(a, b, c, 0, 0, 0)

__device__ __forceinline__ u16 f2b(float x) {   // RNE f32->bf16
  unsigned u = __float_as_uint(x);
  return (u16)((u + 0x7fffu + ((u >> 16) & 1u)) >> 16);
}

// tanh-form GELU (error vs exact erf-GELU <~1e-3; margin is 0.032)
__device__ __forceinline__ float gelu_t(float x) {
  float y = 0.7978845608f * (x + 0.044715f * x * x * x);
  y = fminf(fmaxf(y, -10.f), 10.f);
  float e = __expf(2.f * y);
  return 0.5f * x * (1.f + (e - 1.f) / (e + 1.f));
}

// async global->LDS DMA, 16B/lane; LDS dest = wave-uniform base + lane*16
__device__ __forceinline__ void dma16(const u16* g, void* l) {
  __builtin_amdgcn_global_load_lds(
      (const __attribute__((address_space(1))) void*)g,
      (__attribute__((address_space(3))) void*)l, 16, 0, 0);
}

#define W_QKV (3 * DIM * DIM)   // 786432
#define W_O (DIM * DIM)         // 262144
#define W_1 (DFF * DIM)         // 1048576
#define OFF_O W_QKV
#define OFF_1 (W_QKV + W_O)
#define OFF_2 (W_QKV + W_O + W_1)
#define W_ALL (W_QKV + W_O + 2 * W_1)   // 3145728
#define PREPOST (2 * DIM * DIM)         // 524288
#define N_CVT (PREPOST + NLAYER * W_ALL)   // 19398656

// ---------------- ALL weights f32->bf16, 8 elems/thread, 16B stores
__global__ __launch_bounds__(256) void k_cvt_all(const float* __restrict__ preW,
                                                 const float* __restrict__ postW,
                                                 const float* __restrict__ wq,
                                                 const float* __restrict__ wo,
                                                 const float* __restrict__ w1,
                                                 const float* __restrict__ w2,
                                                 u16* __restrict__ dst) {
  size_t i = ((size_t)blockIdx.x * 256 + threadIdx.x) * 8;   // < N_CVT
  const float* src;
  size_t off;
  if (i < DIM * DIM) { src = preW; off = i; }
  else if (i < PREPOST) { src = postW; off = i - DIM * DIM; }
  else {
    size_t j = i - PREPOST;
    int l = (int)(j / W_ALL);
    size_t r = j - (size_t)l * W_ALL;
    if (r < OFF_O) { src = wq + (size_t)l * W_QKV; off = r; }
    else if (r < OFF_1) { src = wo + (size_t)l * W_O; off = r - OFF_O; }
    else if (r < OFF_2) { src = w1 + (size_t)l * W_1; off = r - OFF_1; }
    else { src = w2 + (size_t)l * W_1; off = r - OFF_2; }
  }
  float4 v0 = *(const float4*)(src + off);
  float4 v1 = *(const float4*)(src + off + 4);
  u16x8 o;
  o[0] = f2b(v0.x); o[1] = f2b(v0.y); o[2] = f2b(v0.z); o[3] = f2b(v0.w);
  o[4] = f2b(v1.x); o[5] = f2b(v1.y); o[6] = f2b(v1.z); o[7] = f2b(v1.w);
  *(u16x8*)(dst + i) = o;
}

// ---------------- patchify -> bf16 A[NTOK][512]
__global__ __launch_bounds__(256) void k_patchify(const float* __restrict__ init,
                                                  const float* __restrict__ endp,
                                                  u16* __restrict__ A) {
  int i = blockIdx.x * 256 + threadIdx.x;
  int d = i & 511;
  int g = i >> 9;
  int p = g & 63;
  int fi = (g >> 6) % FIN;
  int b = g / SEQ;
  int e = fi & 1;
  int pr = fi >> 1;
  int c = d >> 8;
  int r1 = (d >> 4) & 15;
  int r2 = d & 15;
  int row = ((p >> 3) << 4) + r1;
  int col = ((p & 7) << 4) + r2;
  const float* src = e ? endp : init;
  size_t off = ((size_t)((b * PAIRS + pr) * NCH + c) << 14) + (size_t)row * HWP + col;
  A[i] = f2b(src[off]);
}

// ---------------- bf16 MFMA GEMM, 3-stage DMA pipeline (2 tiles in flight;
// vmcnt(2*NC) waits only the tile consumed now — issued 2 compute-periods ago).
// Tile 64(M) x NT(N), BK=32, 4 waves 2x2.  [3-stage = verified-best, round 8]
// MODE 0: outB = act(A·B^T + bias) bf16
// MODE 1: outP = raw f32 partial
// MODE 2: pre epilogue: +bias+patch_pos+func_pos -> outF f32 + outB bf16
// MODE 3: post epilogue: +bias, depatchify scatter -> outF (A compact rows)
// GATHER: A rows are init-slot tokens of a full-layout buffer
template <int NT, int MODE, int GATHER>
__global__ __launch_bounds__(256) void k_mma(const u16* __restrict__ A,
                                             const u16* __restrict__ B,
                                             const float* __restrict__ bias,
                                             u16* __restrict__ outB,
                                             float* __restrict__ outP,
                                             float* __restrict__ outF,
                                             const float* __restrict__ pp,
                                             const float* __restrict__ fp,
                                             int M, int N, int K, int act) {
  constexpr int FJ = NT / 32;             // N-frags per wave
  constexpr int NC = (4 + NT / 16) / 4;   // DMA instrs per wave per stage
  __shared__ __align__(16) bf16_t As[3][64][32];
  __shared__ __align__(16) bf16_t Bs[3][NT][32];
  const int t = threadIdx.x;
  const int w = t >> 6, lane = t & 63, quad = lane >> 4, l16 = lane & 15;
  int bx = blockIdx.x, by = blockIdx.y;
  if ((gridDim.y & 7) == 0) {       // XCD swizzle
    int lin = bx + gridDim.x * by;
    int YT = gridDim.y >> 3;
    int xcd = lin & 7, slot = lin >> 3;
    by = xcd * YT + slot % YT;
    bx = slot / YT;
  }
  const int row0 = by << 6, col0 = bx * NT;
  const int mB = (w & 1) << 5;          // 0 or 32
  const int nB = (w >> 1) * (NT / 2);

  // per-lane A-chunk source pointers
  const u16* aP[4];
#pragma unroll
  for (int c = 0; c < 4; ++c) {
    int r = row0 + c * 16 + (lane >> 2);
    int g = r;
    if (GATHER) {
      int p = r & 63, pr = (r >> 6) % PAIRS, b = r / (PAIRS * PP);
      g = b * SEQ + pr * 128 + p;
    }
    aP[c] = A + (size_t)g * K + ((lane & 3) << 3);
  }
  const u16* bP = B + (size_t)(col0 + (lane >> 2)) * K + ((lane & 3) << 3);

  f32x4 acc[2][FJ];
#pragma unroll
  for (int i = 0; i < 2; ++i)
#pragma unroll
    for (int j = 0; j < FJ; ++j) acc[i][j] = (f32x4){0.f, 0.f, 0.f, 0.f};

  auto stage = [&](int bu, int kk) {
#pragma unroll
    for (int s = 0; s < NC; ++s) {
      int c = NC * w + s;
      if (c < 4) dma16(aP[c] + kk, &As[bu][c * 16][0]);
      else dma16(bP + (size_t)((c - 4) * 16) * K + kk, &Bs[bu][(c - 4) * 16][0]);
    }
  };

  const int iters = K >> 5;
  stage(0, 0);
  stage(1, 32);
  for (int it = 0; it < iters; ++it) {
    const int cur = it % 3;
    if (it > 0) asm volatile("s_barrier" ::: "memory");  // readers of reused buf done
    if (it + 2 < iters) stage((it + 2) % 3, (it + 2) << 5);  // stays in flight
    if (it + 2 < iters) {        // 2 newer tiles in flight -> wait 2*NC
      if (NC == 3) asm volatile("s_waitcnt vmcnt(6)" ::: "memory");
      else asm volatile("s_waitcnt vmcnt(4)" ::: "memory");
    } else if (it + 1 < iters) { // 1 newer tile in flight
      if (NC == 3) asm volatile("s_waitcnt vmcnt(3)" ::: "memory");
      else asm volatile("s_waitcnt vmcnt(2)" ::: "memory");
    } else {
      asm volatile("s_waitcnt vmcnt(0)" ::: "memory");
    }
    asm volatile("s_barrier" ::: "memory");              // all waves' cur DMAs landed
    bf16x8 af[2], bfr[FJ];
#pragma unroll
    for (int i = 0; i < 2; ++i)
      af[i] = *(const bf16x8*)&As[cur][mB + i * 16 + l16][quad * 8];
#pragma unroll
    for (int j = 0; j < FJ; ++j)
      bfr[j] = *(const bf16x8*)&Bs[cur][nB + j * 16 + l16][quad * 8];
#pragma unroll
    for (int i = 0; i < 2; ++i)
#pragma unroll
      for (int j = 0; j < FJ; ++j) acc[i][j] = MFMA16(af[i], bfr[j], acc[i][j]);
  }

#pragma unroll
  for (int i = 0; i < 2; ++i)
#pragma unroll
    for (int reg = 0; reg < 4; ++reg) {
      int m = row0 + mB + i * 16 + quad * 4 + reg;
#pragma unroll
      for (int j = 0; j < FJ; ++j) {
        int n = col0 + nB + j * 16 + l16;
        float v = acc[i][j][reg];
        if (MODE == 0) {
          v += bias[n];
          if (act) v = gelu_t(v);
          outB[(size_t)m * N + n] = f2b(v);
        } else if (MODE == 1) {
          outP[(size_t)m * N + n] = v;
        } else if (MODE == 2) {
          int p = m & 63, fi = (m >> 6) % FIN;
          v += bias[n] + pp[p * DIM + n] + fp[fi * DIM + n];
          outF[(size_t)m * N + n] = v;
          outB[(size_t)m * N + n] = f2b(v);
        } else {   // MODE 3: depatchify scatter (A/m compact init rows)
          v += bias[n];
          int p = m & 63, pr = (m >> 6) % PAIRS, b = m / (PAIRS * PP);
          int c = n >> 8, r1 = (n >> 4) & 15, r2 = n & 15;
          int row = ((p >> 3) << 4) + r1, col = ((p & 7) << 4) + r2;
          size_t off = ((size_t)((b * PAIRS + pr) * NCH + c) << 14) +
                       (size_t)row * HWP + col;
          outF[off] = v;
        }
      }
    }
}

// ---------------- fused flash attention (bf16 MFMA) with next-tile reg prefetch.
// qmul: q-block stride (layer 5 only needs even q-blocks -> qmul=2)
__global__ __launch_bounds__(256) void k_attn(const u16* __restrict__ qkv,
                                              u16* __restrict__ o, int qmul) {
  __shared__ bf16_t Qs[64][72];
  __shared__ bf16_t Ks[64][72];
  __shared__ bf16_t Vs[64][72];   // transposed: Vs[d][tok]
  __shared__ bf16_t Ps[64][72];
  const int t = threadIdx.x;
  const int w = t >> 6, lane = t & 63, quad = lane >> 4, l16 = lane & 15;
  const int qblk = blockIdx.x * qmul, h = blockIdx.y, b = blockIdx.z;
  const int q0 = qblk << 6;
  const u16* base = qkv + (size_t)b * SEQ * (3 * DIM);
  const int sr = t >> 2;
  const int sd = (t & 3) << 4;
  const int rowB = 3 * DIM;
  {
    const u16* qp = base + (size_t)(q0 + sr) * rowB + h * DHEAD + sd;
    *(bf16x8*)&Qs[sr][sd] = *(const bf16x8*)(const void*)qp;
    *(bf16x8*)&Qs[sr][sd + 8] = *(const bf16x8*)(const void*)(qp + 8);
  }
  __syncthreads();
  bf16x8 aQ0 = *(const bf16x8*)&Qs[w * 16 + l16][quad * 8];
  bf16x8 aQ1 = *(const bf16x8*)&Qs[w * 16 + l16][32 + quad * 8];
  f32x4 accO[4];
#pragma unroll
  for (int j = 0; j < 4; ++j) accO[j] = (f32x4){0.f, 0.f, 0.f, 0.f};
  float mSt[4] = {-1e30f, -1e30f, -1e30f, -1e30f};
  float lSt[4] = {0.f, 0.f, 0.f, 0.f};
  const int ntile = qblk + 1;
  const u16* kp0 = base + (size_t)sr * rowB + DIM + h * DHEAD + sd;
  const u16* vp0 = base + (size_t)sr * rowB + 2 * DIM + h * DHEAD + sd;
  bf16x8 kR0 = *(const bf16x8*)(const void*)kp0;
  bf16x8 kR1 = *(const bf16x8*)(const void*)(kp0 + 8);
  bf16x8 vR0 = *(const bf16x8*)(const void*)vp0;
  bf16x8 vR1 = *(const bf16x8*)(const void*)(vp0 + 8);
  for (int kt = 0; kt < ntile; ++kt) {
    *(bf16x8*)&Ks[sr][sd] = kR0;
    *(bf16x8*)&Ks[sr][sd + 8] = kR1;
#pragma unroll
    for (int e = 0; e < 8; ++e) Vs[sd + e][sr] = vR0[e];
#pragma unroll
    for (int e = 0; e < 8; ++e) Vs[sd + 8 + e][sr] = vR1[e];
    if (kt + 1 < ntile) {   // prefetch tile kt+1
      const u16* kp = kp0 + (size_t)(kt + 1) * 64 * rowB;
      const u16* vp = vp0 + (size_t)(kt + 1) * 64 * rowB;
      kR0 = *(const bf16x8*)(const void*)kp;
      kR1 = *(const bf16x8*)(const void*)(kp + 8);
      vR0 = *(const bf16x8*)(const void*)vp;
      vR1 = *(const bf16x8*)(const void*)(vp + 8);
    }
    __syncthreads();
    f32x4 s[4];
#pragma unroll
    for (int j = 0; j < 4; ++j) {
      bf16x8 b0 = *(const bf16x8*)&Ks[j * 16 + l16][quad * 8];
      bf16x8 b1 = *(const bf16x8*)&Ks[j * 16 + l16][32 + quad * 8];
      s[j] = (f32x4){0.f, 0.f, 0.f, 0.f};
      s[j] = MFMA16(aQ0, b0, s[j]);
      s[j] = MFMA16(aQ1, b1, s[j]);
      s[j] *= 0.125f;
    }
#pragma unroll
    for (int reg = 0; reg < 4; ++reg) {
      float mx = fmaxf(fmaxf(s[0][reg], s[1][reg]), fmaxf(s[2][reg], s[3][reg]));
      mx = fmaxf(mx, __shfl_xor(mx, 1));
      mx = fmaxf(mx, __shfl_xor(mx, 2));
      mx = fmaxf(mx, __shfl_xor(mx, 4));
      mx = fmaxf(mx, __shfl_xor(mx, 8));
      float mNew = fmaxf(mSt[reg], mx);
      float alpha = __expf(mSt[reg] - mNew);
      mSt[reg] = mNew;
      float rs = 0.f;
#pragma unroll
      for (int j = 0; j < 4; ++j) {
        float p = __expf(s[j][reg] - mNew);
        s[j][reg] = p;
        rs += p;
      }
      rs += __shfl_xor(rs, 1);
      rs += __shfl_xor(rs, 2);
      rs += __shfl_xor(rs, 4);
      rs += __shfl_xor(rs, 8);
      lSt[reg] = lSt[reg] * alpha + rs;
#pragma unroll
      for (int j = 0; j < 4; ++j) accO[j][reg] *= alpha;
    }
#pragma unroll
    for (int j = 0; j < 4; ++j)
#pragma unroll
      for (int reg = 0; reg < 4; ++reg)
        *(u16*)&Ps[w * 16 + quad * 4 + reg][j * 16 + l16] = f2b(s[j][reg]);
    __syncthreads();
    bf16x8 aP0 = *(const bf16x8*)&Ps[w * 16 + l16][quad * 8];
    bf16x8 aP1 = *(const bf16x8*)&Ps[w * 16 + l16][32 + quad * 8];
#pragma unroll
    for (int jd = 0; jd < 4; ++jd) {
      bf16x8 b0 = *(const bf16x8*)&Vs[jd * 16 + l16][quad * 8];
      bf16x8 b1 = *(const bf16x8*)&Vs[jd * 16 + l16][32 + quad * 8];
      accO[jd] = MFMA16(aP0, b0, accO[jd]);
      accO[jd] = MFMA16(aP1, b1, accO[jd]);
    }
    __syncthreads();
  }
#pragma unroll
  for (int reg = 0; reg < 4; ++reg) {
    float inv = 1.0f / lSt[reg];
    int row = q0 + w * 16 + quad * 4 + reg;
#pragma unroll
    for (int jd = 0; jd < 4; ++jd)
      o[((size_t)(b * SEQ + row)) * DIM + h * DHEAD + jd * 16 + l16] =
          f2b(accO[jd][reg] * inv);
  }
}

// ---------------- reduce + bias + residual + LayerNorm, vectorized.
// 2 rows/block; 128 threads/row; float4/ushort4 accesses. part indexed by r.
// GIN: residual f_in is full-layout, gathered via init-slot map (layer-5 LN1).
template <int GIN>
__global__ __launch_bounds__(256) void k_red_ln(const float* __restrict__ part,
                                                const float* __restrict__ bias,
                                                const float* __restrict__ f_in,
                                                float* __restrict__ f_out,
                                                u16* __restrict__ fb_out,
                                                const float* __restrict__ s,
                                                const float* __restrict__ bvec) {
  const int t = threadIdx.x;
  const int half = t >> 7;                 // row within pair
  const int r = blockIdx.x * 2 + half;
  const int c = (t & 127) * 4;
  int g = r;
  if (GIN) {
    int p = r & 63, pr = (r >> 6) % PAIRS, b = r / (PAIRS * PP);
    g = b * SEQ + pr * 128 + p;
  }
  float4 x = *(const float4*)(f_in + (size_t)g * DIM + c);
  float4 pa = *(const float4*)(part + (size_t)r * DIM + c);
  float4 bi = *(const float4*)(bias + c);
  x.x += pa.x + bi.x; x.y += pa.y + bi.y; x.z += pa.z + bi.z; x.w += pa.w + bi.w;
  float sum = x.x + x.y + x.z + x.w;
  float sq = x.x * x.x + x.y * x.y + x.z * x.z + x.w * x.w;
#pragma unroll
  for (int off = 32; off; off >>= 1) {
    sum += __shfl_xor(sum, off);
    sq += __shfl_xor(sq, off);
  }
  __shared__ float rs[4], rq[4];
  const int w = t >> 6, lane = t & 63;
  if (lane == 0) { rs[w] = sum; rq[w] = sq; }
  __syncthreads();
  float tot = rs[half * 2] + rs[half * 2 + 1];
  float tq2 = rq[half * 2] + rq[half * 2 + 1];
  float mu = tot * (1.0f / 512.0f);
  float var = tq2 * (1.0f / 512.0f) - mu * mu;
  float rstd = rsqrtf(var + 1e-5f);
  float4 sv = *(const float4*)(s + c);
  float4 bv = *(const float4*)(bvec + c);
  float4 o;
  o.x = (x.x - mu) * rstd * sv.x + bv.x;
  o.y = (x.y - mu) * rstd * sv.y + bv.y;
  o.z = (x.z - mu) * rstd * sv.z + bv.z;
  o.w = (x.w - mu) * rstd * sv.w + bv.w;
  *(float4*)(f_out + (size_t)r * DIM + c) = o;
  u16x4 ob;
  ob[0] = f2b(o.x); ob[1] = f2b(o.y); ob[2] = f2b(o.z); ob[3] = f2b(o.w);
  *(u16x4*)(fb_out + (size_t)r * DIM + c) = ob;
}

extern "C" void kernel_launch(void* const* d_in, const int* in_sizes, int n_in,
                              void* d_out, int out_size, void* d_ws, size_t ws_size,
                              hipStream_t stream) {
  const float* init = (const float*)d_in[0];
  const float* endp = (const float*)d_in[1];
  const float* pre_W = (const float*)d_in[3];
  const float* pre_b = (const float*)d_in[4];
  const float* post_W = (const float*)d_in[5];
  const float* post_b = (const float*)d_in[6];
  const float* patch_pos = (const float*)d_in[7];
  const float* func_pos = (const float*)d_in[8];
  const float* Wqkv = (const float*)d_in[9];
  const float* bqkv = (const float*)d_in[10];
  const float* Wo = (const float*)d_in[11];
  const float* bo = (const float*)d_in[12];
  const float* ln1_s = (const float*)d_in[13];
  const float* ln1_b = (const float*)d_in[14];
  const float* ln2_s = (const float*)d_in[15];
  const float* ln2_b = (const float*)d_in[16];
  const float* W1 = (const float*)d_in[17];
  const float* b1 = (const float*)d_in[18];
  const float* W2 = (const float*)d_in[19];
  const float* b2 = (const float*)d_in[20];
  float* out = (float*)d_out;

  // ws layout (~110 MB; ws is 256 MB)
  char* p = (char*)d_ws;
  float* buf_f = (float*)p;    p += (size_t)NTOK * DIM * 4;    // f32 residual master
  u16* buf_fb = (u16*)p;       p += (size_t)NTOK * DIM * 2;    // bf16 stream
  u16* buf_attn = (u16*)p;     p += (size_t)NTOK * DIM * 2;
  u16* shared_b = (u16*)p;     p += (size_t)NTOK * DFF * 2;    // patch/qkv/hid alias
  u16* wAll = (u16*)p;         p += (size_t)N_CVT * 2;         // ALL weights bf16
  float* partial = (float*)p;  p += (size_t)NTOK * DIM * 4;
  float* buf_fc = (float*)p;   p += (size_t)MPOST * DIM * 4;   // layer-5 compact f32
  u16* buf_fbc = (u16*)p;      p += (size_t)MPOST * DIM * 2;   // layer-5 compact bf16
  u16* buf_patch = shared_b;
  u16* buf_qkv = shared_b;
  u16* buf_hid = shared_b;
  u16* wPre = wAll;
  u16* wPost = wAll + DIM * DIM;
  u16* wL = wAll + PREPOST;

  dim3 blk(256);
  const int elems = NTOK * DIM;

  k_cvt_all<<<N_CVT / (256 * 8), blk, 0, stream>>>(pre_W, post_W, Wqkv, Wo, W1, W2,
                                                   wAll);
  k_patchify<<<elems / 256, blk, 0, stream>>>(init, endp, buf_patch);
  // pre GEMM fused with bias+pos epilogue -> buf_f (f32) + buf_fb (bf16)
  k_mma<64, 2, 0><<<dim3(8, 80), blk, 0, stream>>>(
      buf_patch, wPre, pre_b, buf_fb, nullptr, buf_f, patch_pos, func_pos,
      NTOK, DIM, DIM, 0);

  for (int l = 0; l < NLAYER; ++l) {
    u16* wB = wL + (size_t)l * W_ALL;
    k_mma<128, 0, 0><<<dim3(12, 80), blk, 0, stream>>>(
        buf_fb, wB, bqkv + (size_t)l * 3 * DIM, buf_qkv, nullptr, nullptr, nullptr,
        nullptr, NTOK, 3 * DIM, DIM, 0);
    if (l < NLAYER - 1) {
      k_attn<<<dim3(SEQ / 64, NHEAD, BSZ), blk, 0, stream>>>(buf_qkv, buf_attn, 1);
      k_mma<64, 1, 0><<<dim3(8, 80), blk, 0, stream>>>(
          buf_attn, wB + OFF_O, nullptr, nullptr, partial, nullptr, nullptr, nullptr,
          NTOK, DIM, DIM, 0);
      k_red_ln<0><<<NTOK / 2, blk, 0, stream>>>(partial, bo + (size_t)l * DIM,
                                                buf_f, buf_f, buf_fb,
                                                ln1_s + (size_t)l * DIM,
                                                ln1_b + (size_t)l * DIM);
      k_mma<128, 0, 0><<<dim3(16, 80), blk, 0, stream>>>(
          buf_fb, wB + OFF_1, b1 + (size_t)l * DFF, buf_hid, nullptr, nullptr,
          nullptr, nullptr, NTOK, DFF, DIM, 1);
      k_mma<64, 1, 0><<<dim3(8, 80), blk, 0, stream>>>(
          buf_hid, wB + OFF_2, nullptr, nullptr, partial, nullptr, nullptr, nullptr,
          NTOK, DIM, DFF, 0);
      k_red_ln<0><<<NTOK / 2, blk, 0, stream>>>(partial, b2 + (size_t)l * DIM,
                                                buf_f, buf_f, buf_fb,
                                                ln2_s + (size_t)l * DIM,
                                                ln2_b + (size_t)l * DIM);
    } else {
      // layer 5: only init-slot rows matter downstream (exact trim)
      k_attn<<<dim3(SEQ / 128, NHEAD, BSZ), blk, 0, stream>>>(buf_qkv, buf_attn, 2);
      k_mma<64, 1, 1><<<dim3(8, 40), blk, 0, stream>>>(     // proj, gathered A
          buf_attn, wB + OFF_O, nullptr, nullptr, partial, nullptr, nullptr, nullptr,
          MPOST, DIM, DIM, 0);
      k_red_ln<1><<<MPOST / 2, blk, 0, stream>>>(partial, bo + (size_t)l * DIM,
                                                 buf_f, buf_fc, buf_fbc,
                                                 ln1_s + (size_t)l * DIM,
                                                 ln1_b + (size_t)l * DIM);
      k_mma<128, 0, 0><<<dim3(16, 40), blk, 0, stream>>>(
          buf_fbc, wB + OFF_1, b1 + (size_t)l * DFF, buf_hid, nullptr, nullptr,
          nullptr, nullptr, MPOST, DFF, DIM, 1);
      k_mma<64, 1, 0><<<dim3(8, 40), blk, 0, stream>>>(
          buf_hid, wB + OFF_2, nullptr, nullptr, partial, nullptr, nullptr, nullptr,
          MPOST, DIM, DFF, 0);
      k_red_ln<0><<<MPOST / 2, blk, 0, stream>>>(partial, b2 + (size_t)l * DIM,
                                                 buf_fc, buf_fc, buf_fbc,
                                                 ln2_s + (size_t)l * DIM,
                                                 ln2_b + (size_t)l * DIM);
    }
  }

  // post GEMM: compact A rows + bias + depatchify scatter (epilogue)
  k_mma<64, 3, 0><<<dim3(8, 40), blk, 0, stream>>>(
      buf_fbc, wPost, post_b, nullptr, nullptr, out, nullptr, nullptr,
      MPOST, DIM, DIM, 0);
}